// Round 10
// baseline (678.567 us; speedup 1.0000x reference)
//
#include <hip/hip_runtime.h>

#define N_Q   65536
#define N_C   2048
#define KNN_K 16
#define CDIM  64
#define SLCAP 128     // survivor list capacity per query
#define KINF  0x7FFFFFFF
#define WREP  4       // weight image replicas
#define WSZ   108544  // halves per weight image

typedef _Float16 half_t;
typedef float v4f __attribute__((ext_vector_type(4)));
typedef half_t v8h __attribute__((ext_vector_type(8)));

#define ASTRIDE 136   // 128 + 8 pad (halves); row = 272 B = 17*16 B
#define DSTRIDE 40    // 32 + 8 pad

// ---------------------------------------------------------------------------
// Kernel 0: weights -> fp16 MFMA-fragment-order tiles (x4 replicas to spread
// L2 hot-line contention), plus cpos4 = (x,y,z,|c|^2+4).
// ---------------------------------------------------------------------------
__global__ void wtrans_kernel(const float* W0, const float* W1, const float* W2,
                              const float* W3, const float* Wf, const float* Wd,
                              const int* indices, const float* cpos,
                              half_t* wt, float4* cpos4){
  int idx = blockIdx.x * 256 + threadIdx.x;
  if (idx >= 110592) return;
  if (idx >= WSZ){
    int i = idx - WSZ;
    const float* cp = cpos + (size_t)indices[0] * N_C * 3;
    float x = cp[i*3 + 0], y = cp[i*3 + 1], z = cp[i*3 + 2];
    cpos4[i] = make_float4(x, y, z, fmaf(x, x, fmaf(y, y, fmaf(z, z, 4.0f))));
    return;
  }
  int base, nt, mode;            // mode: 0 plain(src), 1 W0, 2 W2, 3 Wd
  const float* src = W1;
  if (idx < 16384){ base = 0; nt = 8; mode = 1; }
  else if (idx < 32768){ base = 16384; nt = 8; mode = 0; src = W1; }
  else if (idx < 65536){ base = 32768; nt = 8; mode = 2; }
  else if (idx < 81920){ base = 65536; nt = 8; mode = 0; src = W3; }
  else if (idx < 98304){ base = 81920; nt = 8; mode = 0; src = Wf; }
  else { base = 98304; nt = 4; mode = 3; }
  int i = idx - base;
  int tile = i >> 9, e = i & 511;
  int lane = e >> 3, j = e & 7;
  int k0idx = tile / nt, tcol = tile - k0idx*nt;
  int n = tcol*16 + (lane & 15);
  int k = k0idx*32 + ((lane >> 4) << 3) + j;
  float val;
  if (mode == 0)      val = src[k*128 + n];
  else if (mode == 1) val = (k < 127) ? W0[k*128 + n] : 0.f;
  else if (mode == 2) val = (k == 127) ? 0.f
                           : ((k < 127) ? W2[k*128 + n] : W2[(k-1)*128 + n]);
  else                val = (k < 155) ? Wd[k*64 + n] : 0.f;
  half_t hv = (half_t)val;
#pragma unroll
  for (int rp = 0; rp < WREP; rp++) wt[rp*WSZ + idx] = hv;
}

// ---------------------------------------------------------------------------
// Exact top-16 selection for one query's p[32] keys (see round-9 notes).
// Returns per-lane keep; lanes 0..15 hold the exact top-16 set.
// ---------------------------------------------------------------------------
__device__ inline int select16(int* p, int* slw, int lane, int l){
  int lm = p[0];
#pragma unroll
  for (int j = 1; j < 32; j++) lm = min(lm, p[j]);

  // sort lane-mins within 16-lane groups (10 stages)
  int v = lm;
#pragma unroll
  for (int k = 2; k <= 16; k <<= 1){
#pragma unroll
    for (int j = k >> 1; j > 0; j >>= 1){
      int o = __shfl_xor(v, j, 64);
      bool dirDesc = (l & k) != 0;
      bool lower   = (l & j) == 0;
      int mn = min(v, o), mx = max(v, o);
      v = (lower != dirDesc) ? mn : mx;
    }
  }
  int t0 = __shfl(v, 3, 64),  t1 = __shfl(v, 19, 64);
  int t2 = __shfl(v, 35, 64), t3 = __shfl(v, 51, 64);
  int tau = max(max(t0, t1), max(t2, t3));   // guarantees n >= 16

  // ballot-compaction
  int n = 0;
#pragma unroll
  for (int j = 0; j < 32; j++){
    bool c = (p[j] <= tau);
    unsigned long long m = __ballot(c);
    if (m){
      if (n <= 64){
        if (c){
          int mb = __builtin_amdgcn_mbcnt_hi((unsigned)(m >> 32),
                   __builtin_amdgcn_mbcnt_lo((unsigned)m, 0));
          slw[n + mb] = p[j];
        }
      }
      n += (int)__popcll(m);
    }
  }
  __builtin_amdgcn_wave_barrier();

  int keep;
  if (n >= KNN_K && n <= 64){
    int x = (lane < n) ? slw[lane] : KINF;
#pragma unroll
    for (int k = 2; k <= 16; k <<= 1){
#pragma unroll
      for (int j = k >> 1; j > 0; j >>= 1){
        int o = __shfl_xor(x, j, 64);
        bool dirDesc = (l & k) != 0;
        bool lower   = (l & j) == 0;
        int mn = min(x, o), mx = max(x, o);
        x = (lower != dirDesc) ? mn : mx;
      }
    }
    x = min(x, __shfl_xor(x, 31, 64));
#pragma unroll
    for (int j = 8; j > 0; j >>= 1){
      int o = __shfl_xor(x, j, 64);
      bool lower = (l & j) == 0;
      int mn = min(x, o), mx = max(x, o);
      x = lower ? mn : mx;
    }
    x = min(x, __shfl_xor(x, 63, 64));
    keep = x;
  } else {
    keep = KINF;
#pragma unroll 1
    for (int rr = 0; rr < KNN_K; rr++){
      int lmf = p[0];
#pragma unroll
      for (int j = 1; j < 32; j++) lmf = min(lmf, p[j]);
      int gm = lmf;
#pragma unroll
      for (int off2 = 1; off2 < 64; off2 <<= 1)
        gm = min(gm, __shfl_xor(gm, off2, 64));
      if (lane == rr) keep = gm;
#pragma unroll
      for (int j = 0; j < 32; j++) p[j] = (p[j] == gm) ? KINF : p[j];
    }
  }
  return keep;
}

// ---------------------------------------------------------------------------
// Kernel 1: exact 16-NN + activation staging. TWO queries per wave (8 waves,
// 16 queries/block): each lp[] read serves both queries' score FMAs, halving
// the ds_read_b128 pipe load per query; the two selection phases give each
// wave two independent dependency chains.
// ---------------------------------------------------------------------------
__global__ __launch_bounds__(512, 4) void knn_kernel(const int* indices,
    const float* qpts, const float4* cpos4, const float* codes,
    const float* xyzdir, half_t* Ain, half_t* Din){
  __shared__ float4 lp[N_C];          // 32 KB
  __shared__ int    sl[16*SLCAP];     // 8 KB
  int tid = threadIdx.x;
  int lane = tid & 63, wave = tid >> 6;
  int l = lane & 15;
  const float* cc = codes + (size_t)indices[0] * N_C * CDIM;

  for (int c = tid; c < N_C; c += 512) lp[c] = cpos4[c];
  __syncthreads();

  int q0 = blockIdx.x * 16 + wave * 2;
  int q1 = q0 + 1;
  float qx0 = qpts[q0*3+0], qy0 = qpts[q0*3+1], qz0 = qpts[q0*3+2];
  float qx1 = qpts[q1*3+0], qy1 = qpts[q1*3+1], qz1 = qpts[q1*3+2];
  float nx0 = -2.f*qx0, ny0 = -2.f*qy0, nz0 = -2.f*qz0;
  float nx1 = -2.f*qx1, ny1 = -2.f*qy1, nz1 = -2.f*qz1;

  int p0[32], p1[32];
#pragma unroll
  for (int j = 0; j < 32; j++){
    int c = j*64 + lane;
    float4 P = lp[c];
    float s0 = fmaf(P.x, nx0, fmaf(P.y, ny0, fmaf(P.z, nz0, P.w)));
    float s1 = fmaf(P.x, nx1, fmaf(P.y, ny1, fmaf(P.z, nz1, P.w)));
    p0[j] = (__float_as_int(s0) & 0xFFFFF800) | c;
    p1[j] = (__float_as_int(s1) & 0xFFFFF800) | c;
  }

  int keep0 = select16(p0, &sl[(wave*2 + 0) * SLCAP], lane, l);
  int keep1 = select16(p1, &sl[(wave*2 + 1) * SLCAP], lane, l);

#pragma unroll
  for (int qq = 0; qq < 2; qq++){
    int q = (qq == 0) ? q0 : q1;
    int keep = (qq == 0) ? keep0 : keep1;
    float qx = (qq == 0) ? qx0 : qx1;
    float qy = (qq == 0) ? qy0 : qy1;
    float qz = (qq == 0) ? qz0 : qz1;

    int ci = keep & 0x7FF;
    float4 P = lp[ci];
    float dx = qx - P.x, dy = qy - P.y, dz = qz - P.z;
    float d2 = fmaf(dz, dz, fmaf(dy, dy, dx*dx));
    float w = 1.0f / (d2 + 1e-16f);
    float wm = (lane < KNN_K) ? w : 0.0f;
#pragma unroll
    for (int off2 = 1; off2 < 64; off2 <<= 1) wm += __shfl_xor(wm, off2, 64);
    float wn = w / wm;

    float acc = 0.f;
#pragma unroll
    for (int i = 0; i < KNN_K; i++){
      int   cb = __shfl(ci, i, 64);
      float wb = __shfl(wn, i, 64);
      acc = fmaf(wb, cc[cb*CDIM + lane], acc);
    }
    size_t arow = (size_t)q * ASTRIDE;
    Ain[arow + lane] = (half_t)acc;

    float xv = (lane < 63) ? xyzdir[(size_t)q*90 + lane] : 0.f;
    Ain[arow + 64 + lane] = (half_t)xv;
    if (lane < 8) Ain[arow + 128 + lane] = (half_t)0.f;
    if (lane < 40){
      float dv = (lane < 27) ? xyzdir[(size_t)q*90 + 63 + lane] : 0.f;
      Din[(size_t)q*DSTRIDE + lane] = (half_t)dv;
    }
  }
}

// ---------------------------------------------------------------------------
// Kernel 2: fused MFMA MLP (structure unchanged from round 9; adds replica
// selection to spread L2 hot-line contention across 4 weight copies).
// ---------------------------------------------------------------------------
template<int NT>
__device__ inline void mfma_sw(const half_t* act, int astride, int rowbase,
                               const half_t* wlayer, int nt, int ktbase,
                               int tcolbase, int kchunk, v4f* acc, int lane){
  int m = lane & 15, quad = lane >> 4;
#pragma unroll
  for (int k0 = 0; k0 < kchunk; k0 += 32){
    v8h a = *(const v8h*)&act[(rowbase + m)*astride + k0 + quad*8];
    int krow = ktbase + (k0 >> 5);
#pragma unroll
    for (int t = 0; t < NT; t++){
      const half_t* bp = wlayer + ((size_t)((krow*nt + tcolbase + t) << 9) + (lane << 3));
      v8h b = *(const v8h*)bp;
      acc[t] = __builtin_amdgcn_mfma_f32_16x16x32_f16(a, b, acc[t], 0, 0, 0);
    }
  }
}

template<int NT>
__device__ inline void epilogue(v4f* acc, half_t* outb, int rowbase, int colbase,
                                const float* bias, bool relu, int lane){
  int n = lane & 15, quad = lane >> 4;
#pragma unroll
  for (int t = 0; t < NT; t++){
    int col = colbase + t*16 + n;
    float bv = bias[col];
#pragma unroll
    for (int r = 0; r < 4; r++){
      float v = acc[t][r] + bv;
      if (relu) v = fmaxf(v, 0.f);
      outb[(rowbase + quad*4 + r)*ASTRIDE + col] = (half_t)v;
    }
  }
}

__global__ __launch_bounds__(256) void mlp_mfma(
    const half_t* Ain, const half_t* Din, const half_t* wtg,
    const float* b0, const float* b1, const float* b2, const float* b3,
    const float* bfb, const float* bdb,
    const float* Wsb, const float* bsb, const float* Wrb, const float* brb,
    float* out){
  __shared__ __align__(16) half_t Abuf[32*ASTRIDE];
  __shared__ __align__(16) half_t Pbuf[32*ASTRIDE];
  __shared__ __align__(16) half_t Qbuf[32*ASTRIDE];
  __shared__ __align__(16) half_t Dbuf[32*DSTRIDE];

  int tid = threadIdx.x, lane = tid & 63, wave = tid >> 6;
  int qbase = blockIdx.x * 32;
  const half_t* wt = wtg + (size_t)((blockIdx.x >> 3) & (WREP - 1)) * WSZ;

  for (int i = tid; i < 32*17; i += 256){
    int r = i / 17, c8 = i - r*17;
    *(uint4*)&Abuf[r*ASTRIDE + (c8 << 3)] =
        *(const uint4*)&Ain[(size_t)(qbase + r)*ASTRIDE + (c8 << 3)];
  }
  for (int i = tid; i < 32*5; i += 256){
    int r = i / 5, c8 = i - r*5;
    *(uint4*)&Dbuf[r*DSTRIDE + (c8 << 3)] =
        *(const uint4*)&Din[(size_t)(qbase + r)*DSTRIDE + (c8 << 3)];
  }
  __syncthreads();

  int rowbase = (wave >> 1) * 16;
  int colhalf = wave & 1;
  int colbase = colhalf * 64;
  int tcolbase = colhalf * 4;
  v4f acc[4];

  const half_t* wt0 = wt;
  const half_t* wt1 = wt + 16384;
  const half_t* wt2 = wt + 32768;
  const half_t* wt3 = wt + 65536;
  const half_t* wtf = wt + 81920;
  const half_t* wtd = wt + 98304;

#define ZACC4() { for (int t_ = 0; t_ < 4; t_++) for (int e_ = 0; e_ < 4; e_++) acc[t_][e_] = 0.f; }

  // L0: A @ W0 -> P (relu)
  ZACC4();
  mfma_sw<4>(Abuf, ASTRIDE, rowbase, wt0, 8, 0, tcolbase, 128, acc, lane);
  epilogue<4>(acc, Pbuf, rowbase, colbase, b0, true, lane);
  __syncthreads();

  // L1: P @ W1 -> Q (relu)
  ZACC4();
  mfma_sw<4>(Pbuf, ASTRIDE, rowbase, wt1, 8, 0, tcolbase, 128, acc, lane);
  epilogue<4>(acc, Qbuf, rowbase, colbase, b1, true, lane);
  __syncthreads();

  // L2: [input_xyz | h1] @ W2 -> P (relu)   (K = 256)
  ZACC4();
  mfma_sw<4>(Abuf, ASTRIDE, rowbase, wt2, 8, 0, tcolbase, 128, acc, lane);
  mfma_sw<4>(Qbuf, ASTRIDE, rowbase, wt2, 8, 4, tcolbase, 128, acc, lane);
  epilogue<4>(acc, Pbuf, rowbase, colbase, b2, true, lane);
  __syncthreads();

  // L3: P @ W3 -> A (h3, kept for sigma)
  ZACC4();
  mfma_sw<4>(Pbuf, ASTRIDE, rowbase, wt3, 8, 0, tcolbase, 128, acc, lane);
  epilogue<4>(acc, Abuf, rowbase, colbase, b3, true, lane);
  __syncthreads();

  // Wf: A(h3) @ Wf -> P (no relu)
  ZACC4();
  mfma_sw<4>(Abuf, ASTRIDE, rowbase, wtf, 8, 0, tcolbase, 128, acc, lane);
  epilogue<4>(acc, Pbuf, rowbase, colbase, bfb, false, lane);
  __syncthreads();

  // Wd: [P(final) | D(dir)] @ Wd -> Q[:,0:64] (relu), N = 64, nt = 4
  int tcolbase_d = colhalf * 2;
  int colbase_d  = colhalf * 32;
  ZACC4();
  mfma_sw<2>(Pbuf, ASTRIDE, rowbase, wtd, 4, 0, tcolbase_d, 128, acc, lane);
  mfma_sw<2>(Dbuf, DSTRIDE, rowbase, wtd, 4, 4, tcolbase_d,  32, acc, lane);
  epilogue<2>(acc, Qbuf, rowbase, colbase_d, bdb, true, lane);
  __syncthreads();

  // Tail: sigma = h3(Abuf).Ws + bs ; rgb = d(Qbuf).Wr + br
  {
    int q = tid >> 3, part = tid & 7;
    float s = 0.f;
#pragma unroll
    for (int k = 0; k < 16; k++){
      int kk = part*16 + k;
      s = fmaf((float)Abuf[q*ASTRIDE + kk], Wsb[kk], s);
    }
    s += __shfl_xor(s, 1, 64); s += __shfl_xor(s, 2, 64); s += __shfl_xor(s, 4, 64);

    float r3[3];
#pragma unroll
    for (int c2 = 0; c2 < 3; c2++){
      float rv = 0.f;
#pragma unroll
      for (int k = 0; k < 8; k++){
        int kk = part*8 + k;
        rv = fmaf((float)Qbuf[q*ASTRIDE + kk], Wrb[kk*3 + c2], rv);
      }
      rv += __shfl_xor(rv, 1, 64); rv += __shfl_xor(rv, 2, 64); rv += __shfl_xor(rv, 4, 64);
      r3[c2] = rv;
    }
    if (part == 0){
      size_t ob = ((size_t)(qbase + q)) * 4;
      out[ob + 0] = r3[0] + brb[0];
      out[ob + 1] = r3[1] + brb[1];
      out[ob + 2] = r3[2] + brb[2];
      out[ob + 3] = s + bsb[0];
    }
  }
}

// ---------------------------------------------------------------------------
extern "C" void kernel_launch(void* const* d_in, const int* in_sizes, int n_in,
                              void* d_out, int out_size, void* d_ws, size_t ws_size,
                              hipStream_t stream){
  (void)in_sizes; (void)n_in; (void)out_size; (void)ws_size;

  const int*   indices = (const int*)d_in[0];
  const float* qpts    = (const float*)d_in[1];
  const float* xyzdir  = (const float*)d_in[2];
  const float* cpos    = (const float*)d_in[3];
  const float* codes   = (const float*)d_in[4];
  const float* W0 = (const float*)d_in[5];
  const float* b0 = (const float*)d_in[6];
  const float* W1 = (const float*)d_in[7];
  const float* b1 = (const float*)d_in[8];
  const float* W2 = (const float*)d_in[9];
  const float* b2 = (const float*)d_in[10];
  const float* W3 = (const float*)d_in[11];
  const float* b3 = (const float*)d_in[12];
  const float* Wf = (const float*)d_in[13];
  const float* bf = (const float*)d_in[14];
  const float* Wd = (const float*)d_in[15];
  const float* bd = (const float*)d_in[16];
  const float* Ws = (const float*)d_in[17];
  const float* bs = (const float*)d_in[18];
  const float* Wr = (const float*)d_in[19];
  const float* br = (const float*)d_in[20];

  // ws layout (16-B aligned): Ain | Din | wt (x4 replicas) | cpos4
  half_t* Ain   = (half_t*)d_ws;                                   // 17,825,792 B
  half_t* Din   = (half_t*)((char*)d_ws + 17825792);               //  5,242,880 B
  half_t* wt    = (half_t*)((char*)d_ws + 17825792 + 5242880);     //  4*217,088 B
  float4* cpos4 = (float4*)((char*)d_ws + 17825792 + 5242880 + (size_t)WREP*WSZ*2);

  wtrans_kernel<<<(110592 + 255)/256, 256, 0, stream>>>(W0, W1, W2, W3, Wf, Wd,
                                                        indices, cpos, wt, cpos4);
  knn_kernel<<<N_Q/16, 512, 0, stream>>>(indices, qpts, cpos4, codes, xyzdir,
                                         Ain, Din);
  mlp_mfma<<<N_Q/32, 256, 0, stream>>>(Ain, Din, wt,
                                       b0, b1, b2, b3, bf, bd, Ws, bs, Wr, br,
                                       (float*)d_out);
}

// Round 11
// 232.160 us; speedup vs baseline: 2.9228x; 2.9228x over previous
//
#include <hip/hip_runtime.h>

#define N_Q   65536
#define N_C   2048
#define KNN_K 16
#define CDIM  64
#define SLCAP 128     // survivor list capacity (overflow -> exact fallback)
#define KINF  0x7FFFFFFF
#define WREP  4       // weight image replicas
#define WSZ   108544  // halves per weight image

typedef _Float16 half_t;
typedef float v4f __attribute__((ext_vector_type(4)));
typedef half_t v8h __attribute__((ext_vector_type(8)));

#define ASTRIDE 136   // 128 + 8 pad (halves); row = 272 B = 17*16 B
#define DSTRIDE 40    // 32 + 8 pad

// ---------------------------------------------------------------------------
// Kernel 0: weights -> fp16 MFMA-fragment-order tiles (x4 replicas to spread
// L2 hot-line contention), plus cpos4 = (x,y,z,|c|^2+4).
// ---------------------------------------------------------------------------
__global__ void wtrans_kernel(const float* W0, const float* W1, const float* W2,
                              const float* W3, const float* Wf, const float* Wd,
                              const int* indices, const float* cpos,
                              half_t* wt, float4* cpos4){
  int idx = blockIdx.x * 256 + threadIdx.x;
  if (idx >= 110592) return;
  if (idx >= WSZ){
    int i = idx - WSZ;
    const float* cp = cpos + (size_t)indices[0] * N_C * 3;
    float x = cp[i*3 + 0], y = cp[i*3 + 1], z = cp[i*3 + 2];
    cpos4[i] = make_float4(x, y, z, fmaf(x, x, fmaf(y, y, fmaf(z, z, 4.0f))));
    return;
  }
  int base, nt, mode;            // mode: 0 plain(src), 1 W0, 2 W2, 3 Wd
  const float* src = W1;
  if (idx < 16384){ base = 0; nt = 8; mode = 1; }
  else if (idx < 32768){ base = 16384; nt = 8; mode = 0; src = W1; }
  else if (idx < 65536){ base = 32768; nt = 8; mode = 2; }
  else if (idx < 81920){ base = 65536; nt = 8; mode = 0; src = W3; }
  else if (idx < 98304){ base = 81920; nt = 8; mode = 0; src = Wf; }
  else { base = 98304; nt = 4; mode = 3; }
  int i = idx - base;
  int tile = i >> 9, e = i & 511;
  int lane = e >> 3, j = e & 7;
  int k0idx = tile / nt, tcol = tile - k0idx*nt;
  int n = tcol*16 + (lane & 15);
  int k = k0idx*32 + ((lane >> 4) << 3) + j;
  float val;
  if (mode == 0)      val = src[k*128 + n];
  else if (mode == 1) val = (k < 127) ? W0[k*128 + n] : 0.f;
  else if (mode == 2) val = (k == 127) ? 0.f
                           : ((k < 127) ? W2[k*128 + n] : W2[(k-1)*128 + n]);
  else                val = (k < 155) ? Wd[k*64 + n] : 0.f;
  half_t hv = (half_t)val;
#pragma unroll
  for (int rp = 0; rp < WREP; rp++) wt[rp*WSZ + idx] = hv;
}

// ---------------------------------------------------------------------------
// Kernel 1: exact 16-NN + activation staging. ONE wave per query (8/block)
// — exact round-9 structure (round-10's 2-query/wave variant spilled p[] to
// scratch: VGPR cap 64 vs ~130 need -> 2.3 GB HBM traffic. Reverted.)
// ---------------------------------------------------------------------------
__global__ __launch_bounds__(512, 8) void knn_kernel(const int* indices,
    const float* qpts, const float4* cpos4, const float* codes,
    const float* xyzdir, half_t* Ain, half_t* Din){
  __shared__ float4 lp[N_C];        // 32 KB
  __shared__ int    sl[8*SLCAP];    // 4 KB
  int tid = threadIdx.x;
  int lane = tid & 63, wave = tid >> 6;
  int l = lane & 15;                // lane within 16-group
  const float* cc = codes + (size_t)indices[0] * N_C * CDIM;

  for (int c = tid; c < N_C; c += 512) lp[c] = cpos4[c];
  __syncthreads();

  int q = blockIdx.x * 8 + wave;
  float qx = qpts[q*3 + 0];
  float qy = qpts[q*3 + 1];
  float qz = qpts[q*3 + 2];
  float nqx = -2.0f*qx, nqy = -2.0f*qy, nqz = -2.0f*qz;

  int p[32];
#pragma unroll
  for (int j = 0; j < 32; j++){
    int c = j*64 + lane;
    float4 P = lp[c];
    float s = fmaf(P.x, nqx, fmaf(P.y, nqy, fmaf(P.z, nqz, P.w)));  // > 0
    p[j] = (__float_as_int(s) & 0xFFFFF800) | c;
  }

  // lane-local min
  int lm = p[0];
#pragma unroll
  for (int j = 1; j < 32; j++) lm = min(lm, p[j]);

  // sort lane-mins ascending WITHIN each 16-lane group (10 stages)
  int v = lm;
#pragma unroll
  for (int k = 2; k <= 16; k <<= 1){
#pragma unroll
    for (int j = k >> 1; j > 0; j >>= 1){
      int o = __shfl_xor(v, j, 64);
      bool dirDesc = (l & k) != 0;
      bool lower   = (l & j) == 0;
      int mn = min(v, o), mx = max(v, o);
      v = (lower != dirDesc) ? mn : mx;
    }
  }
  // tau = max over groups of group's 4th-smallest -> n >= 16 guaranteed
  int t0 = __shfl(v, 3, 64),  t1 = __shfl(v, 19, 64);
  int t2 = __shfl(v, 35, 64), t3 = __shfl(v, 51, 64);
  int tau = max(max(t0, t1), max(t2, t3));

  // ballot-compaction: scalar running n, per-lane position via mbcnt
  int* slw = &sl[wave * SLCAP];
  int n = 0;
#pragma unroll
  for (int j = 0; j < 32; j++){
    bool c = (p[j] <= tau);
    unsigned long long m = __ballot(c);
    if (m){
      if (n <= 64){
        if (c){
          int mb = __builtin_amdgcn_mbcnt_hi((unsigned)(m >> 32),
                   __builtin_amdgcn_mbcnt_lo((unsigned)m, 0));
          slw[n + mb] = p[j];
        }
      }
      n += (int)__popcll(m);
    }
  }
  __builtin_amdgcn_wave_barrier();

  int keep;
  if (n >= KNN_K && n <= 64){
    // top-16-of-64 selection network -> lanes 0..15 hold the top-16 set
    int x = (lane < n) ? slw[lane] : KINF;
#pragma unroll
    for (int k = 2; k <= 16; k <<= 1){
#pragma unroll
      for (int j = k >> 1; j > 0; j >>= 1){
        int o = __shfl_xor(x, j, 64);
        bool dirDesc = (l & k) != 0;
        bool lower   = (l & j) == 0;
        int mn = min(x, o), mx = max(x, o);
        x = (lower != dirDesc) ? mn : mx;
      }
    }
    x = min(x, __shfl_xor(x, 31, 64));
#pragma unroll
    for (int j = 8; j > 0; j >>= 1){
      int o = __shfl_xor(x, j, 64);
      bool lower = (l & j) == 0;
      int mn = min(x, o), mx = max(x, o);
      x = lower ? mn : mx;
    }
    x = min(x, __shfl_xor(x, 63, 64));
    keep = x;
  } else {
    // exact fallback: full rescan extraction over p[32] (rare)
    keep = KINF;
#pragma unroll 1
    for (int rr = 0; rr < KNN_K; rr++){
      int lmf = p[0];
#pragma unroll
      for (int j = 1; j < 32; j++) lmf = min(lmf, p[j]);
      int gm = lmf;
#pragma unroll
      for (int off2 = 1; off2 < 64; off2 <<= 1)
        gm = min(gm, __shfl_xor(gm, off2, 64));
      if (lane == rr) keep = gm;
#pragma unroll
      for (int j = 0; j < 32; j++) p[j] = (p[j] == gm) ? KINF : p[j];
    }
  }

  // exact d2 + inverse-d2 weights (lanes 0..15 meaningful)
  int ci = keep & 0x7FF;
  float4 P = lp[ci];
  float dx = qx - P.x, dy = qy - P.y, dz = qz - P.z;
  float d2 = fmaf(dz, dz, fmaf(dy, dy, dx*dx));
  float w = 1.0f / (d2 + 1e-16f);
  float wm = (lane < KNN_K) ? w : 0.0f;
#pragma unroll
  for (int off2 = 1; off2 < 64; off2 <<= 1) wm += __shfl_xor(wm, off2, 64);
  float wn = w / wm;

  float acc = 0.f;
#pragma unroll
  for (int i = 0; i < KNN_K; i++){
    int   cb = __shfl(ci, i, 64);
    float wb = __shfl(wn, i, 64);
    acc = fmaf(wb, cc[cb*CDIM + lane], acc);
  }
  size_t arow = (size_t)q * ASTRIDE;
  Ain[arow + lane] = (half_t)acc;

  // folded prep: xyzdir -> Ain cols 64..135 (incl. zero pads) and Din
  float xv = (lane < 63) ? xyzdir[(size_t)q*90 + lane] : 0.f;
  Ain[arow + 64 + lane] = (half_t)xv;
  if (lane < 8) Ain[arow + 128 + lane] = (half_t)0.f;
  if (lane < 40){
    float dv = (lane < 27) ? xyzdir[(size_t)q*90 + 63 + lane] : 0.f;
    Din[(size_t)q*DSTRIDE + lane] = (half_t)dv;
  }
}

// ---------------------------------------------------------------------------
// Kernel 2: fused MFMA MLP with replica selection (the round-11 A/B variable:
// spread L2 hot-line contention across 4 weight copies).
// ---------------------------------------------------------------------------
template<int NT>
__device__ inline void mfma_sw(const half_t* act, int astride, int rowbase,
                               const half_t* wlayer, int nt, int ktbase,
                               int tcolbase, int kchunk, v4f* acc, int lane){
  int m = lane & 15, quad = lane >> 4;
#pragma unroll
  for (int k0 = 0; k0 < kchunk; k0 += 32){
    v8h a = *(const v8h*)&act[(rowbase + m)*astride + k0 + quad*8];
    int krow = ktbase + (k0 >> 5);
#pragma unroll
    for (int t = 0; t < NT; t++){
      const half_t* bp = wlayer + ((size_t)((krow*nt + tcolbase + t) << 9) + (lane << 3));
      v8h b = *(const v8h*)bp;
      acc[t] = __builtin_amdgcn_mfma_f32_16x16x32_f16(a, b, acc[t], 0, 0, 0);
    }
  }
}

template<int NT>
__device__ inline void epilogue(v4f* acc, half_t* outb, int rowbase, int colbase,
                                const float* bias, bool relu, int lane){
  int n = lane & 15, quad = lane >> 4;
#pragma unroll
  for (int t = 0; t < NT; t++){
    int col = colbase + t*16 + n;
    float bv = bias[col];
#pragma unroll
    for (int r = 0; r < 4; r++){
      float v = acc[t][r] + bv;
      if (relu) v = fmaxf(v, 0.f);
      outb[(rowbase + quad*4 + r)*ASTRIDE + col] = (half_t)v;
    }
  }
}

__global__ __launch_bounds__(256) void mlp_mfma(
    const half_t* Ain, const half_t* Din, const half_t* wtg,
    const float* b0, const float* b1, const float* b2, const float* b3,
    const float* bfb, const float* bdb,
    const float* Wsb, const float* bsb, const float* Wrb, const float* brb,
    float* out){
  __shared__ __align__(16) half_t Abuf[32*ASTRIDE];
  __shared__ __align__(16) half_t Pbuf[32*ASTRIDE];
  __shared__ __align__(16) half_t Qbuf[32*ASTRIDE];
  __shared__ __align__(16) half_t Dbuf[32*DSTRIDE];

  int tid = threadIdx.x, lane = tid & 63, wave = tid >> 6;
  int qbase = blockIdx.x * 32;
  const half_t* wt = wtg + (size_t)((blockIdx.x >> 3) & (WREP - 1)) * WSZ;

  for (int i = tid; i < 32*17; i += 256){
    int r = i / 17, c8 = i - r*17;
    *(uint4*)&Abuf[r*ASTRIDE + (c8 << 3)] =
        *(const uint4*)&Ain[(size_t)(qbase + r)*ASTRIDE + (c8 << 3)];
  }
  for (int i = tid; i < 32*5; i += 256){
    int r = i / 5, c8 = i - r*5;
    *(uint4*)&Dbuf[r*DSTRIDE + (c8 << 3)] =
        *(const uint4*)&Din[(size_t)(qbase + r)*DSTRIDE + (c8 << 3)];
  }
  __syncthreads();

  int rowbase = (wave >> 1) * 16;
  int colhalf = wave & 1;
  int colbase = colhalf * 64;
  int tcolbase = colhalf * 4;
  v4f acc[4];

  const half_t* wt0 = wt;
  const half_t* wt1 = wt + 16384;
  const half_t* wt2 = wt + 32768;
  const half_t* wt3 = wt + 65536;
  const half_t* wtf = wt + 81920;
  const half_t* wtd = wt + 98304;

#define ZACC4() { for (int t_ = 0; t_ < 4; t_++) for (int e_ = 0; e_ < 4; e_++) acc[t_][e_] = 0.f; }

  // L0: A @ W0 -> P (relu)
  ZACC4();
  mfma_sw<4>(Abuf, ASTRIDE, rowbase, wt0, 8, 0, tcolbase, 128, acc, lane);
  epilogue<4>(acc, Pbuf, rowbase, colbase, b0, true, lane);
  __syncthreads();

  // L1: P @ W1 -> Q (relu)
  ZACC4();
  mfma_sw<4>(Pbuf, ASTRIDE, rowbase, wt1, 8, 0, tcolbase, 128, acc, lane);
  epilogue<4>(acc, Qbuf, rowbase, colbase, b1, true, lane);
  __syncthreads();

  // L2: [input_xyz | h1] @ W2 -> P (relu)   (K = 256)
  ZACC4();
  mfma_sw<4>(Abuf, ASTRIDE, rowbase, wt2, 8, 0, tcolbase, 128, acc, lane);
  mfma_sw<4>(Qbuf, ASTRIDE, rowbase, wt2, 8, 4, tcolbase, 128, acc, lane);
  epilogue<4>(acc, Pbuf, rowbase, colbase, b2, true, lane);
  __syncthreads();

  // L3: P @ W3 -> A (h3, kept for sigma)
  ZACC4();
  mfma_sw<4>(Pbuf, ASTRIDE, rowbase, wt3, 8, 0, tcolbase, 128, acc, lane);
  epilogue<4>(acc, Abuf, rowbase, colbase, b3, true, lane);
  __syncthreads();

  // Wf: A(h3) @ Wf -> P (no relu)
  ZACC4();
  mfma_sw<4>(Abuf, ASTRIDE, rowbase, wtf, 8, 0, tcolbase, 128, acc, lane);
  epilogue<4>(acc, Pbuf, rowbase, colbase, bfb, false, lane);
  __syncthreads();

  // Wd: [P(final) | D(dir)] @ Wd -> Q[:,0:64] (relu), N = 64, nt = 4
  int tcolbase_d = colhalf * 2;
  int colbase_d  = colhalf * 32;
  ZACC4();
  mfma_sw<2>(Pbuf, ASTRIDE, rowbase, wtd, 4, 0, tcolbase_d, 128, acc, lane);
  mfma_sw<2>(Dbuf, DSTRIDE, rowbase, wtd, 4, 4, tcolbase_d,  32, acc, lane);
  epilogue<2>(acc, Qbuf, rowbase, colbase_d, bdb, true, lane);
  __syncthreads();

  // Tail: sigma = h3(Abuf).Ws + bs ; rgb = d(Qbuf).Wr + br
  {
    int q = tid >> 3, part = tid & 7;
    float s = 0.f;
#pragma unroll
    for (int k = 0; k < 16; k++){
      int kk = part*16 + k;
      s = fmaf((float)Abuf[q*ASTRIDE + kk], Wsb[kk], s);
    }
    s += __shfl_xor(s, 1, 64); s += __shfl_xor(s, 2, 64); s += __shfl_xor(s, 4, 64);

    float r3[3];
#pragma unroll
    for (int c2 = 0; c2 < 3; c2++){
      float rv = 0.f;
#pragma unroll
      for (int k = 0; k < 8; k++){
        int kk = part*8 + k;
        rv = fmaf((float)Qbuf[q*ASTRIDE + kk], Wrb[kk*3 + c2], rv);
      }
      rv += __shfl_xor(rv, 1, 64); rv += __shfl_xor(rv, 2, 64); rv += __shfl_xor(rv, 4, 64);
      r3[c2] = rv;
    }
    if (part == 0){
      size_t ob = ((size_t)(qbase + q)) * 4;
      out[ob + 0] = r3[0] + brb[0];
      out[ob + 1] = r3[1] + brb[1];
      out[ob + 2] = r3[2] + brb[2];
      out[ob + 3] = s + bsb[0];
    }
  }
}

// ---------------------------------------------------------------------------
extern "C" void kernel_launch(void* const* d_in, const int* in_sizes, int n_in,
                              void* d_out, int out_size, void* d_ws, size_t ws_size,
                              hipStream_t stream){
  (void)in_sizes; (void)n_in; (void)out_size; (void)ws_size;

  const int*   indices = (const int*)d_in[0];
  const float* qpts    = (const float*)d_in[1];
  const float* xyzdir  = (const float*)d_in[2];
  const float* cpos    = (const float*)d_in[3];
  const float* codes   = (const float*)d_in[4];
  const float* W0 = (const float*)d_in[5];
  const float* b0 = (const float*)d_in[6];
  const float* W1 = (const float*)d_in[7];
  const float* b1 = (const float*)d_in[8];
  const float* W2 = (const float*)d_in[9];
  const float* b2 = (const float*)d_in[10];
  const float* W3 = (const float*)d_in[11];
  const float* b3 = (const float*)d_in[12];
  const float* Wf = (const float*)d_in[13];
  const float* bf = (const float*)d_in[14];
  const float* Wd = (const float*)d_in[15];
  const float* bd = (const float*)d_in[16];
  const float* Ws = (const float*)d_in[17];
  const float* bs = (const float*)d_in[18];
  const float* Wr = (const float*)d_in[19];
  const float* br = (const float*)d_in[20];

  // ws layout (16-B aligned): Ain | Din | wt (x4 replicas) | cpos4
  half_t* Ain   = (half_t*)d_ws;                                   // 17,825,792 B
  half_t* Din   = (half_t*)((char*)d_ws + 17825792);               //  5,242,880 B
  half_t* wt    = (half_t*)((char*)d_ws + 17825792 + 5242880);     //  4*217,088 B
  float4* cpos4 = (float4*)((char*)d_ws + 17825792 + 5242880 + (size_t)WREP*WSZ*2);

  wtrans_kernel<<<(110592 + 255)/256, 256, 0, stream>>>(W0, W1, W2, W3, Wf, Wd,
                                                        indices, cpos, wt, cpos4);
  knn_kernel<<<N_Q/8, 512, 0, stream>>>(indices, qpts, cpos4, codes, xyzdir,
                                        Ain, Din);
  mlp_mfma<<<N_Q/32, 256, 0, stream>>>(Ain, Din, wt,
                                       b0, b1, b2, b3, bf, bd, Ws, bs, Wr, br,
                                       (float*)d_out);
}